// Round 1
// baseline (647.292 us; speedup 1.0000x reference)
//
#include <hip/hip_runtime.h>
#include <hip/hip_bf16.h>
#include <cstdint>

// Problem: B=32, C=32, V=1024, L=13; supports=3, order=2; C_IN=224, C_OUT=64.
// h = concat([x, xA0, xA0^2, xA1, xA1^2, xA2, xA2^2], ch); y = W·h + b
//
// Plan:
//  k_prep_x : x[b,c,v,l] f32 -> T[n=(b,c,l), v] bf16          (27.3 MB)
//  k_prep_A : A_s[v,w] f32   -> AT_s[w,v] bf16                (3x 2 MB)
//  k_prep_W : W[o,cc] f32    -> Wt[cc,o] f32                  (57 KB)
//  k_gemm   : C[n,w] = sum_v X[n,v]*AT[w,v]  (bf16 MFMA, m97 structure)
//             hop1: X=T -> blocks 1,3,5 ; hop2: X=blocks 1,3,5 -> 2,4,6
//  k_final  : y[b,o,v,l] = sum_cc blk[(b,c,l),v]*Wt[cc,o] + bias[o]  (VALU)

#define SZE 13631488          // elems per block: 13312*1024
#define SZB 27262976          // bytes per block (bf16)
#define OFF_AT  190840832ull  // 7*SZB
#define OFF_WT  197132288ull  // OFF_AT + 3*1024*1024*2
#define WS_NEED 197189632ull  // OFF_WT + 224*64*4

typedef __attribute__((ext_vector_type(8))) short short8;
typedef __attribute__((ext_vector_type(4))) float f32x4;

__device__ __forceinline__ unsigned short f2b(float f) {
    unsigned int u = __builtin_bit_cast(unsigned int, f);
    u += 0x7FFFu + ((u >> 16) & 1u);          // round-to-nearest-even
    return (unsigned short)(u >> 16);
}
__device__ __forceinline__ float b2f(unsigned short h) {
    unsigned int u = ((unsigned int)h) << 16;
    return __builtin_bit_cast(float, u);
}

__device__ __forceinline__ void gl2lds16(const unsigned short* g, unsigned short* l) {
    __builtin_amdgcn_global_load_lds(
        (__attribute__((address_space(1))) void*)(g),
        (__attribute__((address_space(3))) void*)(l), 16, 0, 0);
}

// ---------- prep x: [bc, v, l] f32 -> T[(bc*13+l), v] bf16 ----------
__global__ __launch_bounds__(256) void k_prep_x(const float* __restrict__ x,
                                                unsigned short* __restrict__ T) {
    __shared__ unsigned short lb[13312];
    const int bc = blockIdx.x;
    const int t  = threadIdx.x;
    const float* xb = x + (size_t)bc * 13312;
    for (int k = 0; k < 13; ++k) {                 // 3328 float4 = 13*256
        int i4 = k * 256 + t;
        float4 v = ((const float4*)xb)[i4];
        int e = i4 * 4;
        lb[e+0] = f2b(v.x); lb[e+1] = f2b(v.y); lb[e+2] = f2b(v.z); lb[e+3] = f2b(v.w);
    }
    __syncthreads();
    for (int k = 0; k < 13; ++k) {
        int e = (k * 256 + t) * 4;                 // out elem index: l*1024+v
        int l = e >> 10, v0 = e & 1023;
        ushort4 val;
        val.x = lb[(v0+0)*13 + l];
        val.y = lb[(v0+1)*13 + l];
        val.z = lb[(v0+2)*13 + l];
        val.w = lb[(v0+3)*13 + l];
        *(ushort4*)(T + ((size_t)(bc*13 + l) << 10) + v0) = val;
    }
}

// ---------- prep A: A[v,w] f32 -> AT[w,v] bf16, 3 mats ----------
__global__ __launch_bounds__(256) void k_prep_A(const float* __restrict__ A0,
                                                const float* __restrict__ A1,
                                                const float* __restrict__ A2,
                                                unsigned short* __restrict__ AT) {
    const float* A = blockIdx.z == 0 ? A0 : blockIdx.z == 1 ? A1 : A2;
    unsigned short* D = AT + (size_t)blockIdx.z * 1024 * 1024;
    __shared__ float tile[32][33];
    int v0 = blockIdx.y * 32, w0 = blockIdx.x * 32;
    int c = threadIdx.x & 31, r = threadIdx.x >> 5;
    for (int p = 0; p < 4; ++p) {
        int rr = r + p * 8;
        tile[rr][c] = A[(size_t)(v0 + rr) * 1024 + w0 + c];
    }
    __syncthreads();
    for (int p = 0; p < 4; ++p) {
        int rr = r + p * 8;
        D[(size_t)(w0 + rr) * 1024 + v0 + c] = f2b(tile[c][rr]);
    }
}

// ---------- prep W: W[o,cc] -> Wt[cc,o] f32 ----------
__global__ __launch_bounds__(256) void k_prep_W(const float* __restrict__ W,
                                                float* __restrict__ Wt) {
    int idx = blockIdx.x * 256 + threadIdx.x;      // < 14336
    int cc = idx >> 6, o = idx & 63;
    Wt[idx] = W[o * 224 + cc];
}

// ---------- main GEMM: C[n,w] = sum_v X[n,v] * P[w,v], bf16, 128x128 tile ----------
__global__ __launch_bounds__(256) void k_gemm(const unsigned short* __restrict__ Xb, long xstride,
                                              const unsigned short* __restrict__ Pb,
                                              unsigned short* __restrict__ Ob, long ostride) {
    __shared__ union {
        struct { unsigned short xs[4096]; unsigned short ps[4096]; } s;
        unsigned short cs[16384];
    } lds;
    const int z = blockIdx.z;
    const unsigned short* X = Xb + (size_t)z * (size_t)xstride;
    const unsigned short* P = Pb + (size_t)z * (size_t)(1024 * 1024);
    unsigned short*       O = Ob + (size_t)z * (size_t)ostride;
    const int i0 = blockIdx.x * 128;   // n
    const int j0 = blockIdx.y * 128;   // w
    const int t = threadIdx.x;
    const int lane = t & 63, wave = t >> 6;
    const int l16 = lane & 15, quad = lane >> 4;
    const int wi = (wave >> 1) * 64, wj = (wave & 1) * 64;

    f32x4 acc[4][4] = {};

    const int row = t >> 2, seg = t & 3;
    const unsigned short* xg0 = X + (size_t)(i0 + row) * 1024 + seg * 8;
    const unsigned short* xg1 = xg0 + (size_t)64 * 1024;
    const unsigned short* pg0 = P + (size_t)(j0 + row) * 1024 + seg * 8;
    const unsigned short* pg1 = pg0 + (size_t)64 * 1024;
    unsigned short* lx0 = lds.s.xs + t * 8;
    unsigned short* lx1 = lds.s.xs + 2048 + t * 8;
    unsigned short* lp0 = lds.s.ps + t * 8;
    unsigned short* lp1 = lds.s.ps + 2048 + t * 8;

    for (int kt = 0; kt < 32; ++kt) {
        const int ko = kt * 32;
        gl2lds16(xg0 + ko, lx0);
        gl2lds16(xg1 + ko, lx1);
        gl2lds16(pg0 + ko, lp0);
        gl2lds16(pg1 + ko, lp1);
        __syncthreads();
        short8 a[4], b[4];
#pragma unroll
        for (int mi = 0; mi < 4; ++mi)
            a[mi] = *(const short8*)(lds.s.xs + (wi + mi * 16 + l16) * 32 + quad * 8);
#pragma unroll
        for (int nj = 0; nj < 4; ++nj)
            b[nj] = *(const short8*)(lds.s.ps + (wj + nj * 16 + l16) * 32 + quad * 8);
#pragma unroll
        for (int mi = 0; mi < 4; ++mi)
#pragma unroll
            for (int nj = 0; nj < 4; ++nj)
                acc[mi][nj] = __builtin_amdgcn_mfma_f32_16x16x32_bf16(a[mi], b[nj], acc[mi][nj], 0, 0, 0);
        __syncthreads();
    }
    // epilogue: stage fp32->bf16 through LDS, write [n,w] rows coalesced
#pragma unroll
    for (int mi = 0; mi < 4; ++mi)
#pragma unroll
        for (int nj = 0; nj < 4; ++nj)
#pragma unroll
            for (int r = 0; r < 4; ++r)
                lds.cs[(wi + mi * 16 + quad * 4 + r) * 128 + (wj + nj * 16 + l16)] =
                    f2b(acc[mi][nj][r]);
    __syncthreads();
#pragma unroll
    for (int rep = 0; rep < 8; ++rep) {
        int e0 = rep * 2048 + t * 8;
        int rr = e0 >> 7, cc = e0 & 127;
        *(uint4*)(O + (size_t)(i0 + rr) * 1024 + j0 + cc) = *(const uint4*)(lds.cs + e0);
    }
}

// ---------- final 1x1 conv: y[b,o,v,l] = sum_cc blk[(b,c,l),v]*Wt[cc,o] + bias ----------
__global__ __launch_bounds__(256) void k_final(const unsigned short* __restrict__ H,
                                               const float* __restrict__ Wt,
                                               const float* __restrict__ bias,
                                               float* __restrict__ y) {
    __shared__ float sy[64 * 208];
    const int bb = blockIdx.x >> 6;
    const int vt = blockIdx.x & 63;
    const int v0 = vt * 16;
    const int t = threadIdx.x;
    const int vl = t & 15, l = t >> 4;      // l in 0..15, valid < 13
    const int lc = l < 13 ? l : 12;         // clamp: keep control flow uniform
    float acc[64];
#pragma unroll
    for (int o = 0; o < 64; ++o) acc[o] = bias[o];
    const unsigned short* hp = H + (size_t)(bb * 32 * 13 + lc) * 1024 + v0 + vl;
    for (int cc = 0; cc < 224; ++cc) {
        int blk = cc >> 5, c = cc & 31;
        float h = b2f(hp[(size_t)blk * SZE + (size_t)c * 13312]);
        const float4* wrow = (const float4*)(Wt + cc * 64);   // uniform -> s_load
#pragma unroll
        for (int o4 = 0; o4 < 16; ++o4) {
            float4 w = wrow[o4];
            acc[o4 * 4 + 0] += w.x * h;
            acc[o4 * 4 + 1] += w.y * h;
            acc[o4 * 4 + 2] += w.z * h;
            acc[o4 * 4 + 3] += w.w * h;
        }
    }
    if (l < 13) {
        const int r = vl * 13 + l;
#pragma unroll
        for (int o = 0; o < 64; ++o) sy[o * 208 + r] = acc[o];
    }
    __syncthreads();
    float* yb = y + (size_t)bb * 851968 + (size_t)v0 * 13;
#pragma unroll
    for (int rep = 0; rep < 13; ++rep) {
        int q = rep * 256 + t;              // float4 index over 64*208 floats
        int o = q / 52, r4 = q % 52;
        *(float4*)(yb + (size_t)o * 13312 + r4 * 4) = *(const float4*)(sy + o * 208 + r4 * 4);
    }
}

extern "C" void kernel_launch(void* const* d_in, const int* in_sizes, int n_in,
                              void* d_out, int out_size, void* d_ws, size_t ws_size,
                              hipStream_t stream) {
    const float* x    = (const float*)d_in[0];
    const float* A0   = (const float*)d_in[1];
    const float* A1   = (const float*)d_in[2];
    const float* A2   = (const float*)d_in[3];
    const float* W    = (const float*)d_in[4];
    const float* bias = (const float*)d_in[5];
    float* y = (float*)d_out;

    if (ws_size < WS_NEED) return;  // need ~198 MB scratch; fail visibly if short

    unsigned short* Hb = (unsigned short*)d_ws;                    // 7 blocks, bf16
    unsigned short* AT = (unsigned short*)((char*)d_ws + OFF_AT);  // 3x [1024,1024]
    float*          Wt = (float*)((char*)d_ws + OFF_WT);           // [224,64]

    k_prep_x<<<1024, 256, 0, stream>>>(x, Hb);
    k_prep_A<<<dim3(32, 32, 3), 256, 0, stream>>>(A0, A1, A2, AT);
    k_prep_W<<<56, 256, 0, stream>>>(W, Wt);
    // hop1: X = T (xstride 0) -> blocks 1,3,5
    k_gemm<<<dim3(104, 8, 3), 256, 0, stream>>>(Hb, 0L, AT, Hb + (size_t)SZE, (long)(2 * (size_t)SZE));
    // hop2: X = blocks 1,3,5 -> blocks 2,4,6
    k_gemm<<<dim3(104, 8, 3), 256, 0, stream>>>(Hb + (size_t)SZE, (long)(2 * (size_t)SZE), AT,
                                                Hb + (size_t)2 * SZE, (long)(2 * (size_t)SZE));
    k_final<<<2048, 256, 0, stream>>>(Hb, Wt, bias, y);
}

// Round 2
// 551.046 us; speedup vs baseline: 1.1747x; 1.1747x over previous
//
#include <hip/hip_runtime.h>
#include <hip/hip_bf16.h>
#include <cstdint>

// B=32,C=32,V=1024,L=13; 3 supports x order 2; C_IN=224, C_OUT=64.
// Layouts:
//  T-arena (in d_out!): 4 blocks of [n2=(b,l,c), v] bf16 (x-T, h1-T s=0..2)
//  Ht (ws): [m=(b*1024+v)*13+l, cc=224] bf16 -- cc-contiguous for final MFMA
//  hop GEMM: C[n2,w] = sum_v X[n2,v]*AT[w,v]; epilogue writes [n2,v] (hop1)
//            and transposed 64B c-slices into Ht (both hops)
//  k_fc: y[m,o] = sum_cc Ht[m,cc]*W[o,cc] + bias, MFMA K=224, 208-row tiles

#define SZE 13631488ull        // elems per [13312,1024] block
#define OFF_AT  190840832ull   // Ht bytes = 425984*224*2
#define OFF_WB  197132288ull   // OFF_AT + 3*1024*1024*2
#define WS_NEED 197160960ull   // OFF_WB + 64*224*2

typedef __attribute__((ext_vector_type(8))) short short8;
typedef __attribute__((ext_vector_type(4))) float f32x4;

__device__ __forceinline__ unsigned short f2b(float f) {
    unsigned int u = __builtin_bit_cast(unsigned int, f);
    u += 0x7FFFu + ((u >> 16) & 1u);          // round-to-nearest-even
    return (unsigned short)(u >> 16);
}

__device__ __forceinline__ void gl2lds16(const unsigned short* g, unsigned short* l) {
    __builtin_amdgcn_global_load_lds(
        (__attribute__((address_space(1))) void*)(g),
        (__attribute__((address_space(3))) void*)(l), 16, 0, 0);
}

// ---------- prep x: x[b,c,v,l] f32 -> T[n2=(b*13+l)*32+c, v] bf16 ----------
__global__ __launch_bounds__(256) void k_prep_x(const float* __restrict__ x,
                                                unsigned short* __restrict__ T) {
    __shared__ unsigned short lb[13312];      // [v][l] bf16 plane for one (b,c)
    const int bc = blockIdx.x;
    const int b = bc >> 5, c = bc & 31;
    const int t = threadIdx.x;
    const float* xb = x + (size_t)bc * 13312;
    for (int k = 0; k < 13; ++k) {
        int i4 = k * 256 + t;
        float4 v = ((const float4*)xb)[i4];
        int e = i4 * 4;
        lb[e+0] = f2b(v.x); lb[e+1] = f2b(v.y); lb[e+2] = f2b(v.z); lb[e+3] = f2b(v.w);
    }
    __syncthreads();
    for (int l = 0; l < 13; ++l) {
        int v0 = t * 4;
        ushort4 val;
        val.x = lb[(v0+0)*13 + l];
        val.y = lb[(v0+1)*13 + l];
        val.z = lb[(v0+2)*13 + l];
        val.w = lb[(v0+3)*13 + l];
        *(ushort4*)(T + ((size_t)((b*13 + l)*32 + c) << 10) + v0) = val;
    }
}

// ---------- prep A: A[v,w] f32 -> AT[w,v] bf16, 3 mats ----------
__global__ __launch_bounds__(256) void k_prep_A(const float* __restrict__ A0,
                                                const float* __restrict__ A1,
                                                const float* __restrict__ A2,
                                                unsigned short* __restrict__ AT) {
    const float* A = blockIdx.z == 0 ? A0 : blockIdx.z == 1 ? A1 : A2;
    unsigned short* D = AT + (size_t)blockIdx.z * 1024 * 1024;
    __shared__ float tile[32][33];
    int v0 = blockIdx.y * 32, w0 = blockIdx.x * 32;
    int c = threadIdx.x & 31, r = threadIdx.x >> 5;
    for (int p = 0; p < 4; ++p) {
        int rr = r + p * 8;
        tile[rr][c] = A[(size_t)(v0 + rr) * 1024 + w0 + c];
    }
    __syncthreads();
    for (int p = 0; p < 4; ++p) {
        int rr = r + p * 8;
        D[(size_t)(w0 + rr) * 1024 + v0 + c] = f2b(tile[c][rr]);
    }
}

// ---------- prep W: W[o,cc] f32 -> Wb[o,cc] bf16 ----------
__global__ __launch_bounds__(256) void k_prep_W(const float* __restrict__ W,
                                                unsigned short* __restrict__ Wb) {
    int idx = blockIdx.x * 256 + threadIdx.x;  // 14336 = 56*256
    Wb[idx] = f2b(W[idx]);
}

// ---------- block-0 transpose: T[n2,v] -> Ht[(b*1024+v)*13+l, 0:32] ----------
__global__ __launch_bounds__(256) void k_h0t(const unsigned short* __restrict__ T,
                                             unsigned short* __restrict__ Ht) {
    __shared__ unsigned short tb[416 * 64];   // [l*32+c][vi]
    const int b  = blockIdx.x >> 4;
    const int v0 = (blockIdx.x & 15) * 64;
    const int t  = threadIdx.x;
    const unsigned short* Tb = T + (size_t)b * 416 * 1024;
    for (int it = 0; it < 13; ++it) {
        int q = it * 256 + t;                 // 3328 16B chunks
        int row = q >> 3, seg = q & 7;
        *(uint4*)(tb + row * 64 + seg * 8) =
            *(const uint4*)(Tb + (size_t)row * 1024 + v0 + seg * 8);
    }
    __syncthreads();
    for (int it = 0; it < 4; ++it) {
        int p = it * 256 + t;                 // 832 (vi,l) pairs
        if (p < 832) {
            int vi = p & 63, l = p >> 6;
            ushort4 pk[4];
#pragma unroll
            for (int j = 0; j < 4; ++j) {
                ushort4 u;
                u.x = tb[(l * 32 + j * 4 + 0) * 64 + vi];   // note: c = j*4.. wrong order?
                u.y = tb[(l * 32 + j * 4 + 1) * 64 + vi];
                u.z = tb[(l * 32 + j * 4 + 2) * 64 + vi];
                u.w = tb[(l * 32 + j * 4 + 3) * 64 + vi];
                pk[j] = u;
            }
            // pk covers c = 0..15 in groups of 4; second half below
            size_t m = (size_t)b * 13312 + (size_t)(v0 + vi) * 13 + l;
            unsigned short* dst = Ht + m * 224;
#pragma unroll
            for (int j = 0; j < 4; ++j) *(ushort4*)(dst + j * 4) = pk[j];
#pragma unroll
            for (int j = 0; j < 4; ++j) {
                ushort4 u;
                u.x = tb[(l * 32 + 16 + j * 4 + 0) * 64 + vi];
                u.y = tb[(l * 32 + 16 + j * 4 + 1) * 64 + vi];
                u.z = tb[(l * 32 + 16 + j * 4 + 2) * 64 + vi];
                u.w = tb[(l * 32 + 16 + j * 4 + 3) * 64 + vi];
                *(ushort4*)(dst + 16 + j * 4) = u;
            }
        }
    }
}

// ---------- hop GEMM: C[n2,w] = sum_v X[n2,v]*P[w,v], 128x128 bf16 tiles ----------
__global__ __launch_bounds__(256) void k_gemm(const unsigned short* __restrict__ Xb, long xz,
                                              const unsigned short* __restrict__ Pb,
                                              unsigned short* __restrict__ Tout, long tz,
                                              unsigned short* __restrict__ Ht, int cc0b,
                                              int doT) {
    __shared__ union {
        struct { unsigned short xs[4096]; unsigned short ps[4096]; } s;
        unsigned short cs[16384];             // [n][v] for T-layout write
        unsigned short ct[128 * 136];         // [v][n] (pad 8) for Ht write
    } lds;
    const int z = blockIdx.z;
    const unsigned short* X = Xb + (size_t)z * (size_t)xz;
    const unsigned short* P = Pb + (size_t)z * (1024u * 1024u);
    const int i0 = blockIdx.x * 128;          // n2
    const int j0 = blockIdx.y * 128;          // w
    const int t = threadIdx.x;
    const int lane = t & 63, wave = t >> 6;
    const int l16 = lane & 15, quad = lane >> 4;
    const int wi = (wave >> 1) * 64, wj = (wave & 1) * 64;

    f32x4 acc[4][4] = {};

    const int row = t >> 2, seg = t & 3;
    const unsigned short* xg0 = X + (size_t)(i0 + row) * 1024 + seg * 8;
    const unsigned short* xg1 = xg0 + (size_t)64 * 1024;
    const unsigned short* pg0 = P + (size_t)(j0 + row) * 1024 + seg * 8;
    const unsigned short* pg1 = pg0 + (size_t)64 * 1024;
    unsigned short* lx0 = lds.s.xs + t * 8;
    unsigned short* lx1 = lds.s.xs + 2048 + t * 8;
    unsigned short* lp0 = lds.s.ps + t * 8;
    unsigned short* lp1 = lds.s.ps + 2048 + t * 8;

    for (int kt = 0; kt < 32; ++kt) {
        const int ko = kt * 32;
        gl2lds16(xg0 + ko, lx0);
        gl2lds16(xg1 + ko, lx1);
        gl2lds16(pg0 + ko, lp0);
        gl2lds16(pg1 + ko, lp1);
        __syncthreads();
        short8 a[4], b[4];
#pragma unroll
        for (int mi = 0; mi < 4; ++mi)
            a[mi] = *(const short8*)(lds.s.xs + (wi + mi * 16 + l16) * 32 + quad * 8);
#pragma unroll
        for (int nj = 0; nj < 4; ++nj)
            b[nj] = *(const short8*)(lds.s.ps + (wj + nj * 16 + l16) * 32 + quad * 8);
#pragma unroll
        for (int mi = 0; mi < 4; ++mi)
#pragma unroll
            for (int nj = 0; nj < 4; ++nj)
                acc[mi][nj] = __builtin_amdgcn_mfma_f32_16x16x32_bf16(a[mi], b[nj], acc[mi][nj], 0, 0, 0);
        __syncthreads();
    }

    // ---- epilogue A: [n2, v] write for hop-2 consumption (hop1 only) ----
    if (doT) {
#pragma unroll
        for (int mi = 0; mi < 4; ++mi)
#pragma unroll
            for (int nj = 0; nj < 4; ++nj)
#pragma unroll
                for (int r = 0; r < 4; ++r)
                    lds.cs[(wi + mi * 16 + quad * 4 + r) * 128 + (wj + nj * 16 + l16)] =
                        f2b(acc[mi][nj][r]);
        __syncthreads();
        unsigned short* O = Tout + (size_t)z * (size_t)tz;
#pragma unroll
        for (int rep = 0; rep < 8; ++rep) {
            int e0 = rep * 2048 + t * 8;
            int rr = e0 >> 7, cc = e0 & 127;
            *(uint4*)(O + (size_t)(i0 + rr) * 1024 + j0 + cc) = *(const uint4*)(lds.cs + e0);
        }
        __syncthreads();
    }

    // ---- epilogue B: transposed stage [v][n], write Ht c-slices ----
#pragma unroll
    for (int mi = 0; mi < 4; ++mi)
#pragma unroll
        for (int nj = 0; nj < 4; ++nj) {
            ushort4 pk;
            pk.x = f2b(acc[mi][nj][0]);
            pk.y = f2b(acc[mi][nj][1]);
            pk.z = f2b(acc[mi][nj][2]);
            pk.w = f2b(acc[mi][nj][3]);
            *(ushort4*)(lds.ct + (wj + nj * 16 + l16) * 136 + wi + mi * 16 + quad * 4) = pk;
        }
    __syncthreads();
    const int cc0 = cc0b + 64 * z;
#pragma unroll
    for (int it = 0; it < 8; ++it) {
        int q = it * 256 + t;                 // 2048 16B chunks: 4 slabs x 128 v x 4 seg
        int sg = q & 3, v = (q >> 2) & 127, s = q >> 9;
        int p = (i0 >> 5) + s;                // slab = b*13 + l
        int b = p / 13, l = p - b * 13;
        size_t m = (size_t)b * 13312 + (size_t)(j0 + v) * 13 + l;
        *(uint4*)(Ht + m * 224 + cc0 + sg * 8) =
            *(const uint4*)(lds.ct + v * 136 + s * 32 + sg * 8);
    }
}

// ---------- final conv: y[m,o] = sum_cc Ht[m,cc]*W[o,cc] + bias, MFMA ----------
__global__ __launch_bounds__(256) void k_fc(const unsigned short* __restrict__ Ht,
                                            const unsigned short* __restrict__ Wb,
                                            const float* __restrict__ bias,
                                            float* __restrict__ y) {
    __shared__ union {
        struct { unsigned short w[64 * 232]; unsigned short a[208 * 40]; } s;
        float sy[64 * 212];
    } lds;
    const int bid = blockIdx.x;
    const int b = bid >> 6, v0 = (bid & 63) * 16;
    const size_t m0 = (size_t)b * 13312 + (size_t)v0 * 13;
    const int t = threadIdx.x;
    const int lane = t & 63, wave = t >> 6;
    const int l16 = lane & 15, quad = lane >> 4;
    const int o0 = wave * 16;

    // stage W: 64x224 -> sW (row pad to 232)
    for (int it = 0; it < 7; ++it) {
        int q = it * 256 + t;                 // 1792 uint4
        int o = q / 28, sg = q % 28;
        *(uint4*)(lds.s.w + o * 232 + sg * 8) = *(const uint4*)(Wb + o * 224 + sg * 8);
    }
    float bv = bias[o0 + l16];
    f32x4 acc[13];
#pragma unroll
    for (int mf = 0; mf < 13; ++mf) acc[mf] = (f32x4){bv, bv, bv, bv};

    for (int kk = 0; kk < 7; ++kk) {
        __syncthreads();
        for (int it = 0; it < 4; ++it) {
            int q = it * 256 + t;             // 832 16B chunks: 208 rows x 4
            if (q < 832) {
                int r = q >> 2, sg = q & 3;
                *(uint4*)(lds.s.a + r * 40 + sg * 8) =
                    *(const uint4*)(Ht + (m0 + r) * 224 + kk * 32 + sg * 8);
            }
        }
        __syncthreads();
        short8 bf = *(const short8*)(lds.s.w + (o0 + l16) * 232 + kk * 32 + quad * 8);
#pragma unroll
        for (int mf = 0; mf < 13; ++mf) {
            short8 af = *(const short8*)(lds.s.a + (mf * 16 + l16) * 40 + quad * 8);
            acc[mf] = __builtin_amdgcn_mfma_f32_16x16x32_bf16(af, bf, acc[mf], 0, 0, 0);
        }
    }
    __syncthreads();
#pragma unroll
    for (int mf = 0; mf < 13; ++mf)
#pragma unroll
        for (int r = 0; r < 4; ++r)
            lds.sy[(o0 + l16) * 212 + mf * 16 + quad * 4 + r] = acc[mf][r];
    __syncthreads();
    float* yb = y + (size_t)b * 851968 + (size_t)v0 * 13;
    for (int it = 0; it < 13; ++it) {
        int q = it * 256 + t;                 // 3328 float4: 64 o x 52
        int o = q / 52, sg = q % 52;
        *(float4*)(yb + (size_t)o * 13312 + sg * 4) = *(const float4*)(lds.sy + o * 212 + sg * 4);
    }
}

extern "C" void kernel_launch(void* const* d_in, const int* in_sizes, int n_in,
                              void* d_out, int out_size, void* d_ws, size_t ws_size,
                              hipStream_t stream) {
    const float* x    = (const float*)d_in[0];
    const float* A0   = (const float*)d_in[1];
    const float* A1   = (const float*)d_in[2];
    const float* A2   = (const float*)d_in[3];
    const float* W    = (const float*)d_in[4];
    const float* bias = (const float*)d_in[5];

    if (ws_size < WS_NEED) return;

    unsigned short* Ht = (unsigned short*)d_ws;
    unsigned short* AT = (unsigned short*)((char*)d_ws + OFF_AT);
    unsigned short* Wb = (unsigned short*)((char*)d_ws + OFF_WB);
    unsigned short* Tarena = (unsigned short*)d_out;   // 4 x SZE bf16 == out bytes exactly

    k_prep_x<<<1024, 256, 0, stream>>>(x, Tarena);
    k_prep_A<<<dim3(32, 32, 3), 256, 0, stream>>>(A0, A1, A2, AT);
    k_prep_W<<<56, 256, 0, stream>>>(W, Wb);
    k_h0t<<<512, 256, 0, stream>>>(Tarena, Ht);
    // hop1: X = x-T -> h1-T (blocks 1,3,5 of Ht at cc0 = 32+64z) + [n2,v] copies
    k_gemm<<<dim3(104, 8, 3), 256, 0, stream>>>(Tarena, 0L, AT,
                                                Tarena + SZE, (long)SZE, Ht, 32, 1);
    // hop2: X = h1-T -> Ht blocks 2,4,6 (cc0 = 64+64z), no T write
    k_gemm<<<dim3(104, 8, 3), 256, 0, stream>>>(Tarena + SZE, (long)SZE, AT,
                                                nullptr, 0L, Ht, 64, 0);
    k_fc<<<2048, 256, 0, stream>>>(Ht, Wb, bias, (float*)d_out);
}

// Round 3
// 510.992 us; speedup vs baseline: 1.2667x; 1.0784x over previous
//
#include <hip/hip_runtime.h>
#include <hip/hip_bf16.h>
#include <cstdint>

// B=32,C=32,V=1024,L=13; 3 supports x order 2; C_IN=224, C_OUT=64.
//  T-arena (in d_out): 4 blocks of [n2=(b,l,c), v] bf16 (x-T, h1-T s=0..2)
//  Ht (ws): [m=(b*1024+v)*13+l, cc=224] bf16 -- cc-contiguous for final MFMA
//  k_prep: x -> T block0 rows + Ht cc0..31 (fused transpose, one LDS tile)
//  k_gemm: C[n2,w]=sum_v X[n2,v]*AT[w,v]; 2-plane staging (K=64/barrier);
//          epilogue A ([n2,v] for hop2, stride-132 LDS) + B (Ht c-slices)
//  k_fc:   y[m,o]=sum_cc Ht[m,cc]*W[o,cc]+bias; A staged via global_load_lds

#define SZE 13631488ull        // elems per [13312,1024] block
#define OFF_AT  190840832ull   // Ht bytes = 425984*224*2
#define OFF_WB  197132288ull   // OFF_AT + 3*1024*1024*2
#define WS_NEED 197160960ull   // OFF_WB + 64*224*2

typedef __attribute__((ext_vector_type(8))) short short8;
typedef __attribute__((ext_vector_type(4))) float f32x4;

__device__ __forceinline__ unsigned short f2b(float f) {
    unsigned int u = __builtin_bit_cast(unsigned int, f);
    u += 0x7FFFu + ((u >> 16) & 1u);          // round-to-nearest-even
    return (unsigned short)(u >> 16);
}

__device__ __forceinline__ void gl2lds16(const unsigned short* g, unsigned short* l) {
    __builtin_amdgcn_global_load_lds(
        (__attribute__((address_space(1))) void*)(g),
        (__attribute__((address_space(3))) void*)(l), 16, 0, 0);
}

// ---------- fused prep: x[b,c,v,l] f32 -> T rows (block0) + Ht cc0..31 ----------
__global__ __launch_bounds__(256) void k_prep(const float* __restrict__ x,
                                              unsigned short* __restrict__ T,
                                              unsigned short* __restrict__ Ht) {
    __shared__ unsigned short sb[32 * 840];   // [c][e=v*13+l], 832 padded to 840
    const int b = blockIdx.x >> 4, vc = blockIdx.x & 15;
    const int t = threadIdx.x;
    const float4* xb = (const float4*)x;
    // phase 1: load+convert. sb[c][e] = bf16(x[(b*32+c)][vc*64 + e/13][e%13])
    for (int it = 0; it < 26; ++it) {
        int q = it * 256 + t;                 // 6656 = 32c * 208f4
        int c = q / 208, f = q - c * 208;
        float4 u = xb[(size_t)(b * 32 + c) * 3328 + vc * 208 + f];
        ushort4 pk; pk.x = f2b(u.x); pk.y = f2b(u.y); pk.z = f2b(u.z); pk.w = f2b(u.w);
        *(ushort4*)(sb + c * 840 + f * 4) = pk;
    }
    __syncthreads();
    // phase 2: T rows  T[(b*13+l)*32+c][vc*64 + 0..63]
    unsigned short* Tb = T + (size_t)b * 13 * 32 * 1024 + (size_t)vc * 64;
    for (int it = 0; it < 26; ++it) {
        int q = it * 256 + t;                 // 6656 = 13l * 32c * 16sg
        int l = q >> 9, r = q & 511, c = r >> 4, sg = r & 15;
        const unsigned short* src = sb + c * 840 + l;
        ushort4 pk;
        pk.x = src[(sg * 4 + 0) * 13];
        pk.y = src[(sg * 4 + 1) * 13];
        pk.z = src[(sg * 4 + 2) * 13];
        pk.w = src[(sg * 4 + 3) * 13];
        *(ushort4*)(Tb + (size_t)(l * 32 + c) * 1024 + sg * 4) = pk;
    }
    // phase 3: Ht rows  Ht[b*13312 + (vc*64+v)*13 + l][0..31]
    unsigned short* Hb = Ht + ((size_t)b * 13312 + (size_t)vc * 832) * 224;
    for (int it = 0; it < 26; ++it) {
        int q = it * 256 + t;                 // 6656 = 64v * 13l * 8cs
        int v = q / 104, r = q - v * 104, l = r >> 3, cs = r & 7;
        const unsigned short* src = sb + v * 13 + l;
        ushort4 pk;
        pk.x = src[(cs * 4 + 0) * 840];
        pk.y = src[(cs * 4 + 1) * 840];
        pk.z = src[(cs * 4 + 2) * 840];
        pk.w = src[(cs * 4 + 3) * 840];
        *(ushort4*)(Hb + (size_t)(v * 13 + l) * 224 + cs * 4) = pk;
    }
}

// ---------- prep A: A[v,w] f32 -> AT[w,v] bf16, 3 mats ----------
__global__ __launch_bounds__(256) void k_prep_A(const float* __restrict__ A0,
                                                const float* __restrict__ A1,
                                                const float* __restrict__ A2,
                                                unsigned short* __restrict__ AT) {
    const float* A = blockIdx.z == 0 ? A0 : blockIdx.z == 1 ? A1 : A2;
    unsigned short* D = AT + (size_t)blockIdx.z * 1024 * 1024;
    __shared__ float tile[32][33];
    int v0 = blockIdx.y * 32, w0 = blockIdx.x * 32;
    int c = threadIdx.x & 31, r = threadIdx.x >> 5;
    for (int p = 0; p < 4; ++p) {
        int rr = r + p * 8;
        tile[rr][c] = A[(size_t)(v0 + rr) * 1024 + w0 + c];
    }
    __syncthreads();
    for (int p = 0; p < 4; ++p) {
        int rr = r + p * 8;
        D[(size_t)(w0 + rr) * 1024 + v0 + c] = f2b(tile[c][rr]);
    }
}

// ---------- prep W: W[o,cc] f32 -> Wb[o,cc] bf16 ----------
__global__ __launch_bounds__(256) void k_prep_W(const float* __restrict__ W,
                                                unsigned short* __restrict__ Wb) {
    int idx = blockIdx.x * 256 + threadIdx.x;  // 14336 = 56*256
    Wb[idx] = f2b(W[idx]);
}

// ---------- hop GEMM: C[n2,w] = sum_v X[n2,v]*P[w,v], 128x128 bf16 tiles ----------
// 2-plane K staging: K=64 per barrier pair (two BK=32 planes).
__global__ __launch_bounds__(256) void k_gemm(const unsigned short* __restrict__ Xb, long xz,
                                              const unsigned short* __restrict__ Pb,
                                              unsigned short* __restrict__ Tout, long tz,
                                              unsigned short* __restrict__ Ht, int cc0b,
                                              int doT) {
    __shared__ union {
        struct { unsigned short xs[8192]; unsigned short ps[8192]; } s;  // 2 planes each
        unsigned short cs[128 * 132];         // [n][v], stride 132 (bank spread)
        unsigned short ct[128 * 136];         // [v][n] for Ht write (34816 B max)
    } lds;
    const int z = blockIdx.z;
    const unsigned short* X = Xb + (size_t)z * (size_t)xz;
    const unsigned short* P = Pb + (size_t)z * (1024u * 1024u);
    const int i0 = blockIdx.x * 128;          // n2
    const int j0 = blockIdx.y * 128;          // w
    const int t = threadIdx.x;
    const int lane = t & 63, wave = t >> 6;
    const int l16 = lane & 15, quad = lane >> 4;
    const int wi = (wave >> 1) * 64, wj = (wave & 1) * 64;

    f32x4 acc[4][4] = {};

    const int row = t >> 2, seg = t & 3;
    const unsigned short* xg0 = X + (size_t)(i0 + row) * 1024 + seg * 8;
    const unsigned short* xg1 = xg0 + (size_t)64 * 1024;
    const unsigned short* pg0 = P + (size_t)(j0 + row) * 1024 + seg * 8;
    const unsigned short* pg1 = pg0 + (size_t)64 * 1024;
    unsigned short* lx0 = lds.s.xs + t * 8;          // plane0 rows 0..63
    unsigned short* lp0 = lds.s.ps + t * 8;

    for (int kt = 0; kt < 16; ++kt) {
        const int ko = kt * 64;
        gl2lds16(xg0 + ko,      lx0);
        gl2lds16(xg1 + ko,      lx0 + 2048);         // plane0 rows 64..127
        gl2lds16(xg0 + ko + 32, lx0 + 4096);         // plane1
        gl2lds16(xg1 + ko + 32, lx0 + 6144);
        gl2lds16(pg0 + ko,      lp0);
        gl2lds16(pg1 + ko,      lp0 + 2048);
        gl2lds16(pg0 + ko + 32, lp0 + 4096);
        gl2lds16(pg1 + ko + 32, lp0 + 6144);
        __syncthreads();
#pragma unroll
        for (int p = 0; p < 2; ++p) {
            short8 a[4], b[4];
#pragma unroll
            for (int mi = 0; mi < 4; ++mi)
                a[mi] = *(const short8*)(lds.s.xs + p * 4096 + (wi + mi * 16 + l16) * 32 + quad * 8);
#pragma unroll
            for (int nj = 0; nj < 4; ++nj)
                b[nj] = *(const short8*)(lds.s.ps + p * 4096 + (wj + nj * 16 + l16) * 32 + quad * 8);
#pragma unroll
            for (int mi = 0; mi < 4; ++mi)
#pragma unroll
                for (int nj = 0; nj < 4; ++nj)
                    acc[mi][nj] = __builtin_amdgcn_mfma_f32_16x16x32_bf16(a[mi], b[nj], acc[mi][nj], 0, 0, 0);
        }
        __syncthreads();
    }

    // ---- epilogue A: [n2, v] write for hop-2 consumption (hop1 only) ----
    if (doT) {
#pragma unroll
        for (int mi = 0; mi < 4; ++mi)
#pragma unroll
            for (int nj = 0; nj < 4; ++nj)
#pragma unroll
                for (int r = 0; r < 4; ++r)
                    lds.cs[(wi + mi * 16 + quad * 4 + r) * 132 + (wj + nj * 16 + l16)] =
                        f2b(acc[mi][nj][r]);
        __syncthreads();
        unsigned short* O = Tout + (size_t)z * (size_t)tz;
#pragma unroll
        for (int rep = 0; rep < 8; ++rep) {
            int q = rep * 256 + t;            // 2048 16B chunks: 128 rows x 16
            int rr = q >> 4, sg = q & 15;
            *(uint4*)(O + (size_t)(i0 + rr) * 1024 + j0 + sg * 8) =
                *(const uint4*)(lds.cs + rr * 132 + sg * 8);
        }
        __syncthreads();
    }

    // ---- epilogue B: transposed stage [v][n], write Ht c-slices ----
#pragma unroll
    for (int mi = 0; mi < 4; ++mi)
#pragma unroll
        for (int nj = 0; nj < 4; ++nj) {
            ushort4 pk;
            pk.x = f2b(acc[mi][nj][0]);
            pk.y = f2b(acc[mi][nj][1]);
            pk.z = f2b(acc[mi][nj][2]);
            pk.w = f2b(acc[mi][nj][3]);
            *(ushort4*)(lds.ct + (wj + nj * 16 + l16) * 136 + wi + mi * 16 + quad * 4) = pk;
        }
    __syncthreads();
    const int cc0 = cc0b + 64 * z;
#pragma unroll
    for (int it = 0; it < 8; ++it) {
        int q = it * 256 + t;                 // 2048 16B chunks: 4 slabs x 128 v x 4 seg
        int sg = q & 3, v = (q >> 2) & 127, s = q >> 9;
        int p = (i0 >> 5) + s;                // slab = b*13 + l
        int b = p / 13, l = p - b * 13;
        size_t m = (size_t)b * 13312 + (size_t)(j0 + v) * 13 + l;
        *(uint4*)(Ht + m * 224 + cc0 + sg * 8) =
            *(const uint4*)(lds.ct + v * 136 + s * 32 + sg * 8);
    }
}

// ---------- final conv: y[m,o] = sum_cc Ht[m,cc]*W[o,cc] + bias, MFMA ----------
__global__ __launch_bounds__(256) void k_fc(const unsigned short* __restrict__ Ht,
                                            const unsigned short* __restrict__ Wb,
                                            const float* __restrict__ bias,
                                            float* __restrict__ y) {
    __shared__ union {
        struct { unsigned short w[64 * 232]; unsigned short a[208 * 32]; } s;
        float sy[64 * 212];
    } lds;
    const int bid = blockIdx.x;
    const int b = bid >> 6, v0 = (bid & 63) * 16;
    const size_t m0 = (size_t)b * 13312 + (size_t)v0 * 13;
    const int t = threadIdx.x;
    const int lane = t & 63, wave = t >> 6;
    const int l16 = lane & 15, quad = lane >> 4;
    const int o0 = wave * 16;

    // stage W: 64x224 -> sW (row pad to 232; 2-way banks = free)
    for (int it = 0; it < 7; ++it) {
        int q = it * 256 + t;                 // 1792 uint4
        int o = q / 28, sg = q % 28;
        *(uint4*)(lds.s.w + o * 232 + sg * 8) = *(const uint4*)(Wb + o * 224 + sg * 8);
    }
    float bv = bias[o0 + l16];
    f32x4 acc[13];
#pragma unroll
    for (int mf = 0; mf < 13; ++mf) acc[mf] = (f32x4){bv, bv, bv, bv};

    for (int kk = 0; kk < 7; ++kk) {
        __syncthreads();                      // protects W (kk=0) / prior A reads
        for (int it = 0; it < 4; ++it) {
            int q = it * 256 + t;             // 832 16B chunks: 208 rows x 4
            if (q < 832)
                gl2lds16(Ht + (m0 + (q >> 2)) * 224 + kk * 32 + (q & 3) * 8,
                         lds.s.a + q * 8);
        }
        __syncthreads();
        short8 bf = *(const short8*)(lds.s.w + (o0 + l16) * 232 + kk * 32 + quad * 8);
#pragma unroll
        for (int mf = 0; mf < 13; ++mf) {
            short8 af = *(const short8*)(lds.s.a + (mf * 16 + l16) * 32 + quad * 8);
            acc[mf] = __builtin_amdgcn_mfma_f32_16x16x32_bf16(af, bf, acc[mf], 0, 0, 0);
        }
    }
    __syncthreads();
#pragma unroll
    for (int mf = 0; mf < 13; ++mf)
#pragma unroll
        for (int r = 0; r < 4; ++r)
            lds.sy[(o0 + l16) * 212 + mf * 16 + quad * 4 + r] = acc[mf][r];
    __syncthreads();
    float* yb = y + (size_t)b * 851968 + (size_t)v0 * 13;
    for (int it = 0; it < 13; ++it) {
        int q = it * 256 + t;                 // 3328 float4: 64 o x 52
        int o = q / 52, sg = q % 52;
        *(float4*)(yb + (size_t)o * 13312 + sg * 4) = *(const float4*)(lds.sy + o * 212 + sg * 4);
    }
}

extern "C" void kernel_launch(void* const* d_in, const int* in_sizes, int n_in,
                              void* d_out, int out_size, void* d_ws, size_t ws_size,
                              hipStream_t stream) {
    const float* x    = (const float*)d_in[0];
    const float* A0   = (const float*)d_in[1];
    const float* A1   = (const float*)d_in[2];
    const float* A2   = (const float*)d_in[3];
    const float* W    = (const float*)d_in[4];
    const float* bias = (const float*)d_in[5];

    if (ws_size < WS_NEED) return;

    unsigned short* Ht = (unsigned short*)d_ws;
    unsigned short* AT = (unsigned short*)((char*)d_ws + OFF_AT);
    unsigned short* Wb = (unsigned short*)((char*)d_ws + OFF_WB);
    unsigned short* Tarena = (unsigned short*)d_out;   // 4 x SZE bf16 == out bytes exactly

    k_prep<<<512, 256, 0, stream>>>(x, Tarena, Ht);
    k_prep_A<<<dim3(32, 32, 3), 256, 0, stream>>>(A0, A1, A2, AT);
    k_prep_W<<<56, 256, 0, stream>>>(W, Wb);
    // hop1: X = x-T -> h1-T (Ht cc0 = 32+64z) + [n2,v] copies for hop2
    k_gemm<<<dim3(104, 8, 3), 256, 0, stream>>>(Tarena, 0L, AT,
                                                Tarena + SZE, (long)SZE, Ht, 32, 1);
    // hop2: X = h1-T -> Ht blocks (cc0 = 64+64z), no T write
    k_gemm<<<dim3(104, 8, 3), 256, 0, stream>>>(Tarena + SZE, (long)SZE, AT,
                                                nullptr, 0L, Ht, 64, 0);
    k_fc<<<2048, 256, 0, stream>>>(Ht, Wb, bias, (float*)d_out);
}